// Round 5
// baseline (953.583 us; speedup 1.0000x reference)
//
#include <hip/hip_runtime.h>
#include <stdint.h>

#define N_TOK 16384
#define D_IN  2048
#define D_OUT 2048
#define NEXP  8

#define BM 256
#define BN 128
#define BK 32
#define NKT (D_IN / BK)  // 64 K-tiles
#define NX4 (N_TOK * D_IN / 4)
#define NW4 (NEXP * D_OUT * D_IN / 4)

typedef __attribute__((ext_vector_type(8))) short bf16x8;
typedef __attribute__((ext_vector_type(4))) float f32x4;
typedef __attribute__((ext_vector_type(4))) unsigned short u16x4;

static __device__ __forceinline__ unsigned short f2bf(float x) {
  unsigned u = __builtin_bit_cast(unsigned, x);
  u += 0x7FFFu + ((u >> 16) & 1u);  // round-to-nearest-even
  return (unsigned short)(u >> 16);
}
static __device__ __forceinline__ float bf2f(unsigned short h) {
  unsigned u = ((unsigned)h) << 16;
  return __builtin_bit_cast(float, u);
}

// ---------------- routing (per-block LDS histogram) ----------------
__global__ void zero_cnt(int* cnt) {
  if (threadIdx.x < NEXP) cnt[threadIdx.x] = 0;
}

__global__ void route_kernel(const int* __restrict__ idxs, int* __restrict__ cnt,
                             int* __restrict__ bucket) {
  __shared__ int hist[NEXP];
  __shared__ int base[NEXP];
  __shared__ int pos[NEXP];
  const int t = blockIdx.x * 256 + threadIdx.x;  // N_TOK % 256 == 0
  if (threadIdx.x < NEXP) { hist[threadIdx.x] = 0; pos[threadIdx.x] = 0; }
  __syncthreads();
  const int e = idxs[t];
  atomicAdd(&hist[e], 1);
  __syncthreads();
  if (threadIdx.x < NEXP)
    base[threadIdx.x] = atomicAdd(&cnt[threadIdx.x], hist[threadIdx.x]);
  __syncthreads();
  const int r = atomicAdd(&pos[e], 1);
  bucket[e * N_TOK + base[e] + r] = t;
}

// ---------------- fused fp32 -> bf16 hi/lo split for x AND W ----------------
__global__ void split_both(const float* __restrict__ x, const float* __restrict__ W,
                           unsigned short* __restrict__ xhi, unsigned short* __restrict__ xlo,
                           unsigned short* __restrict__ whi, unsigned short* __restrict__ wlo) {
  const int total = NX4 + NW4;
  for (int i = blockIdx.x * blockDim.x + threadIdx.x; i < total; i += gridDim.x * blockDim.x) {
    const bool isx = (i < NX4);  // NX4 % (grid*block) == 0 -> wave-uniform
    const int j = isx ? i : i - NX4;
    const float4 v = isx ? ((const float4*)x)[j] : ((const float4*)W)[j];
    float f[4] = {v.x, v.y, v.z, v.w};
    u16x4 h, l;
#pragma unroll
    for (int k = 0; k < 4; ++k) {
      unsigned short hh = f2bf(f[k]);
      h[k] = hh;
      l[k] = f2bf(f[k] - bf2f(hh));
    }
    unsigned short* dh = (isx ? xhi : whi) + (size_t)j * 4;
    unsigned short* dl = (isx ? xlo : wlo) + (size_t)j * 4;
    *(u16x4*)dh = h;
    *(u16x4*)dl = l;
  }
}

// ---------------- grouped gather-GEMM: 256x128 tile, distance-2 counted-vmcnt pipeline ----
// Buffer (48KB): A-tile [0,32K): 256 rows x 128B; B-tile [32K,48K): 128 rows x 128B.
// Row = [hi k0..31 | lo k0..31] bf16; 16B chunks XOR-swizzled: phys = logical ^ (row&7).
// Staged via global_load_lds (linear LDS dest, inverse-swizzled per-lane global source).
#define GLD16(g, l)                                                                    \
  __builtin_amdgcn_global_load_lds((const __attribute__((address_space(1))) void*)(g), \
                                   (__attribute__((address_space(3))) void*)(l), 16, 0, 0)
#define SB() __builtin_amdgcn_sched_barrier(0)
#define BAR() __builtin_amdgcn_s_barrier()

__global__ __launch_bounds__(512)
void moe_gemm(const unsigned short* __restrict__ xhi, const unsigned short* __restrict__ xlo,
              const unsigned short* __restrict__ whi, const unsigned short* __restrict__ wlo,
              const float* __restrict__ bias, const int* __restrict__ cnt,
              const int* __restrict__ bucket, float* __restrict__ out) {
  // XCD-aware decomposition: bid&7 = XCD residue = expert; within expert,
  // consecutive co-resident blocks cover all 16 N-tiles of 2 M-tiles (A L2-reuse x16).
  const int bid = blockIdx.x;
  const int e = bid & 7;
  const int rem = bid >> 3;
  const int my = rem >> 4;
  const int nb = rem & 15;
  const int count = cnt[e];
  const int m0 = my * BM;
  if (m0 >= count) return;  // uniform early exit before any barrier
  const int n0 = nb * BN;

  __shared__ __align__(16) char sbuf[3][49152];
  __shared__ int rowtok[BM];

  const int tid = threadIdx.x;
  const int lane = tid & 63;
  const int w = tid >> 6;
  const int wrM = (w >> 1) * 64;  // wave-row: 64 A-rows
  const int wcN = (w & 1) * 64;   // wave-col: 64 B-rows

  if (tid < BM) {
    int r = m0 + tid;
    rowtok[tid] = bucket[e * N_TOK + (r < count ? r : count - 1)];
  }
  __syncthreads();

  // Per-thread staging sources: 6 rounds per K-tile (4 A-rounds, 2 B-rounds).
  // Round q, thread t writes LDS offset region + t*16 (wave-uniform base + lane*16).
  // row g = t>>3 within 64-row group; phys chunk = t&7; logical c = (t&7)^(g&7);
  // half = c>>2 (hi/lo array), kc = c&3 (16B k-chunk).
  const unsigned short* whiE = whi + (size_t)e * D_OUT * D_IN;
  const unsigned short* wloE = wlo + (size_t)e * D_OUT * D_IN;
  const unsigned short* srcb[6];
  {
    const int g = tid >> 3;
    const int c = (tid & 7) ^ (g & 7);
    const int half = c >> 2, kc = c & 3;
#pragma unroll
    for (int q = 0; q < 4; ++q) {
      const int tok = rowtok[q * 64 + g];
      srcb[q] = (half ? xlo : xhi) + (size_t)tok * D_IN + kc * 8;
    }
#pragma unroll
    for (int q = 0; q < 2; ++q) {
      srcb[4 + q] = (half ? wloE : whiE) + (size_t)(n0 + q * 64 + g) * D_IN + kc * 8;
    }
  }
  const int dstw = w * 1024;  // wave-uniform LDS dest base

  // ds-read per-lane byte offset: row base R (mult of 16) + (lane&15);
  // logical chunk = half*4 + (lane>>4); phys = chunk ^ (lane&7); lo-half = ^64.
  const int off0 = (lane & 15) * 128 + (((lane >> 4) ^ (lane & 7)) * 16);

  f32x4 acc[4][4];
#pragma unroll
  for (int i = 0; i < 4; ++i)
#pragma unroll
    for (int j = 0; j < 4; ++j) acc[i][j] = (f32x4)0.0f;

  // Prologue: stage tiles 0 and 1, wait for tile 0 only (vmcnt(6) leaves tile 1 in flight).
#pragma unroll
  for (int q = 0; q < 4; ++q) GLD16(srcb[q], sbuf[0] + q * 8192 + dstw);
#pragma unroll
  for (int q = 0; q < 2; ++q) GLD16(srcb[4 + q], sbuf[0] + 32768 + q * 8192 + dstw);
#pragma unroll
  for (int q = 0; q < 4; ++q) GLD16(srcb[q] + BK, sbuf[1] + q * 8192 + dstw);
#pragma unroll
  for (int q = 0; q < 2; ++q) GLD16(srcb[4 + q] + BK, sbuf[1] + 32768 + q * 8192 + dstw);
  SB();
  asm volatile("s_waitcnt vmcnt(6)" ::: "memory");
  BAR(); SB();

#define COMPUTE(rb)                                                              \
  {                                                                              \
    bf16x8 ah[4], al[4], bh[4], bl[4];                                           \
    _Pragma("unroll") for (int m = 0; m < 4; ++m) {                              \
      const char* p = (rb) + (wrM + m * 16) * 128;                               \
      ah[m] = *(const bf16x8*)(p + off0);                                        \
      al[m] = *(const bf16x8*)(p + (off0 ^ 64));                                 \
    }                                                                            \
    _Pragma("unroll") for (int n = 0; n < 4; ++n) {                              \
      const char* p = (rb) + 32768 + (wcN + n * 16) * 128;                       \
      bh[n] = *(const bf16x8*)(p + off0);                                        \
      bl[n] = *(const bf16x8*)(p + (off0 ^ 64));                                 \
    }                                                                            \
    __builtin_amdgcn_s_setprio(1);                                               \
    _Pragma("unroll") for (int m = 0; m < 4; ++m)                                \
    _Pragma("unroll") for (int n = 0; n < 4; ++n) {                              \
      f32x4 a = acc[m][n];                                                       \
      a = __builtin_amdgcn_mfma_f32_16x16x32_bf16(ah[m], bh[n], a, 0, 0, 0);     \
      a = __builtin_amdgcn_mfma_f32_16x16x32_bf16(ah[m], bl[n], a, 0, 0, 0);     \
      a = __builtin_amdgcn_mfma_f32_16x16x32_bf16(al[m], bh[n], a, 0, 0, 0);     \
      acc[m][n] = a;                                                             \
    }                                                                            \
    __builtin_amdgcn_s_setprio(0);                                               \
  }

  // Main loop: compute tile i from buf i%3 while staging tile i+2 into buf (i+2)%3.
  // Close waits vmcnt(6): tile i+1 (issued last iter) forced landed; tile i+2 stays
  // in flight. One barrier per tile; buffer written is 2 tiles from any reader.
  int i = 0;
  for (; i < NKT - 2; ++i) {
    const char* rb = sbuf[i % 3];
    char* wb = sbuf[(i + 2) % 3];
    const int kt = (i + 2) * BK;
#pragma unroll
    for (int q = 0; q < 4; ++q) GLD16(srcb[q] + kt, wb + q * 8192 + dstw);
#pragma unroll
    for (int q = 0; q < 2; ++q) GLD16(srcb[4 + q] + kt, wb + 32768 + q * 8192 + dstw);
    SB();
    COMPUTE(rb);
    SB();
    asm volatile("s_waitcnt vmcnt(6)" ::: "memory");
    BAR(); SB();
  }
  // i = NKT-2: compute, then full drain (tile NKT-1 must land)
  {
    const char* rb = sbuf[i % 3];
    COMPUTE(rb);
    SB();
    asm volatile("s_waitcnt vmcnt(0)" ::: "memory");
    BAR(); SB();
    ++i;
  }
  // i = NKT-1: last tile, no close needed
  {
    const char* rb = sbuf[i % 3];
    COMPUTE(rb);
  }

  // epilogue: bias + ReLU + scatter (C/D: col=lane&15, row=(lane>>4)*4+i)
  const int r16 = lane & 15;
  const int rb4 = (lane >> 4) * 4;
#pragma unroll
  for (int n = 0; n < 4; ++n) {
    const int gn = n0 + wcN + n * 16 + r16;
    const float bv = bias[e * D_OUT + gn];
#pragma unroll
    for (int m = 0; m < 4; ++m) {
      const int lr = wrM + m * 16 + rb4;
#pragma unroll
      for (int i2 = 0; i2 < 4; ++i2) {
        const int row = lr + i2;
        if (m0 + row < count) {
          out[(size_t)rowtok[row] * D_OUT + gn] = fmaxf(acc[m][n][i2] + bv, 0.0f);
        }
      }
    }
  }
#undef COMPUTE
}

// ---------------- slow-but-correct fallback (only if ws too small) ----------------
__global__ void fallback_kernel(const float* __restrict__ x, const int* __restrict__ idxs,
                                const float* __restrict__ W, const float* __restrict__ b,
                                float* __restrict__ out) {
  const int row = blockIdx.y;
  const int col = blockIdx.x * 256 + threadIdx.x;
  const int e = idxs[row];
  const float4* xr = (const float4*)(x + (size_t)row * D_IN);
  const float4* wr = (const float4*)(W + ((size_t)e * D_OUT + col) * D_IN);
  float acc = 0.f;
  for (int k = 0; k < D_IN / 4; ++k) {
    float4 a = xr[k], w = wr[k];
    acc += a.x * w.x + a.y * w.y + a.z * w.z + a.w * w.w;
  }
  out[(size_t)row * D_OUT + col] = fmaxf(acc + b[e * D_OUT + col], 0.0f);
}

extern "C" void kernel_launch(void* const* d_in, const int* in_sizes, int n_in,
                              void* d_out, int out_size, void* d_ws, size_t ws_size,
                              hipStream_t stream) {
  const float* x = (const float*)d_in[0];
  const int* idxs = (const int*)d_in[1];
  const float* W = (const float*)d_in[2];
  const float* b = (const float*)d_in[3];
  float* out = (float*)d_out;

  size_t off = 0;
  auto alloc = [&](size_t bytes) {
    void* p = (char*)d_ws + off;
    off += (bytes + 255) & ~(size_t)255;
    return p;
  };
  int* cnt = (int*)alloc(NEXP * sizeof(int));
  int* bucket = (int*)alloc((size_t)NEXP * N_TOK * sizeof(int));
  unsigned short* xhi = (unsigned short*)alloc((size_t)N_TOK * D_IN * 2);
  unsigned short* xlo = (unsigned short*)alloc((size_t)N_TOK * D_IN * 2);
  unsigned short* whi = (unsigned short*)alloc((size_t)NEXP * D_OUT * D_IN * 2);
  unsigned short* wlo = (unsigned short*)alloc((size_t)NEXP * D_OUT * D_IN * 2);

  if (off > ws_size) {
    dim3 g(D_OUT / 256, N_TOK, 1);
    fallback_kernel<<<g, 256, 0, stream>>>(x, idxs, W, b, out);
    return;
  }

  zero_cnt<<<1, 64, 0, stream>>>(cnt);
  route_kernel<<<N_TOK / 256, 256, 0, stream>>>(idxs, cnt, bucket);
  split_both<<<2048, 256, 0, stream>>>(x, W, xhi, xlo, whi, wlo);

  const int nblk = NEXP * (N_TOK / BM) * (D_OUT / BN);  // 8192
  moe_gemm<<<nblk, 512, 0, stream>>>(xhi, xlo, whi, wlo, b, cnt, bucket, out);
}

// Round 6
// 898.835 us; speedup vs baseline: 1.0609x; 1.0609x over previous
//
#include <hip/hip_runtime.h>
#include <stdint.h>

#define N_TOK 16384
#define D_IN  2048
#define D_OUT 2048
#define NEXP  8

#define BM 256
#define BN 256
#define BK 32
#define NKT (D_IN / BK)  // 64 K-tiles
#define NX4 (N_TOK * D_IN / 4)
#define NW4 (NEXP * D_OUT * D_IN / 4)

typedef __attribute__((ext_vector_type(8))) short bf16x8;
typedef __attribute__((ext_vector_type(4))) float f32x4;
typedef __attribute__((ext_vector_type(4))) unsigned short u16x4;

static __device__ __forceinline__ unsigned short f2bf(float x) {
  unsigned u = __builtin_bit_cast(unsigned, x);
  u += 0x7FFFu + ((u >> 16) & 1u);  // round-to-nearest-even
  return (unsigned short)(u >> 16);
}
static __device__ __forceinline__ float bf2f(unsigned short h) {
  unsigned u = ((unsigned)h) << 16;
  return __builtin_bit_cast(float, u);
}

// ---------------- routing (per-block LDS histogram) ----------------
__global__ void zero_cnt(int* cnt) {
  if (threadIdx.x < NEXP) cnt[threadIdx.x] = 0;
}

__global__ void route_kernel(const int* __restrict__ idxs, int* __restrict__ cnt,
                             int* __restrict__ bucket) {
  __shared__ int hist[NEXP];
  __shared__ int base[NEXP];
  __shared__ int pos[NEXP];
  const int t = blockIdx.x * 256 + threadIdx.x;  // N_TOK % 256 == 0
  if (threadIdx.x < NEXP) { hist[threadIdx.x] = 0; pos[threadIdx.x] = 0; }
  __syncthreads();
  const int e = idxs[t];
  atomicAdd(&hist[e], 1);
  __syncthreads();
  if (threadIdx.x < NEXP)
    base[threadIdx.x] = atomicAdd(&cnt[threadIdx.x], hist[threadIdx.x]);
  __syncthreads();
  const int r = atomicAdd(&pos[e], 1);
  bucket[e * N_TOK + base[e] + r] = t;
}

// ---------------- fused fp32 -> bf16 hi/lo split for x AND W ----------------
__global__ void split_both(const float* __restrict__ x, const float* __restrict__ W,
                           unsigned short* __restrict__ xhi, unsigned short* __restrict__ xlo,
                           unsigned short* __restrict__ whi, unsigned short* __restrict__ wlo) {
  const int total = NX4 + NW4;
  for (int i = blockIdx.x * blockDim.x + threadIdx.x; i < total; i += gridDim.x * blockDim.x) {
    const bool isx = (i < NX4);  // NX4 % (grid*block) == 0 -> wave-uniform
    const int j = isx ? i : i - NX4;
    const float4 v = isx ? ((const float4*)x)[j] : ((const float4*)W)[j];
    float f[4] = {v.x, v.y, v.z, v.w};
    u16x4 h, l;
#pragma unroll
    for (int k = 0; k < 4; ++k) {
      unsigned short hh = f2bf(f[k]);
      h[k] = hh;
      l[k] = f2bf(f[k] - bf2f(hh));
    }
    unsigned short* dh = (isx ? xhi : whi) + (size_t)j * 4;
    unsigned short* dl = (isx ? xlo : wlo) + (size_t)j * 4;
    *(u16x4*)dh = h;
    *(u16x4*)dl = l;
  }
}

// ---------------- grouped gather-GEMM: 256x256, 8 waves, counted-vmcnt dbuf ----------------
// Buffer (64KB): A [0,32K): 256 rows x 128B; B [32K,64K): 256 rows x 128B.
// Row = [hi k0..31 | lo k0..31] bf16; 16B chunks XOR-swizzled: phys = logical ^ (row&7).
// Staged via global_load_lds (linear LDS dest, inverse-swizzled per-lane global source).
// Per iter: BAR (WAR gate) -> issue 8 GLDs (tile i+1) -> vmcnt(8) [tile i landed; i+1
// stays in flight -- NEVER 0 in main loop] -> BAR -> 2 phases {ds_read | setprio MFMA}.
#define GLD16(g, l)                                                                    \
  __builtin_amdgcn_global_load_lds((const __attribute__((address_space(1))) void*)(g), \
                                   (__attribute__((address_space(3))) void*)(l), 16, 0, 0)
#define SB() __builtin_amdgcn_sched_barrier(0)
#define BAR() __builtin_amdgcn_s_barrier()

__global__ __launch_bounds__(512)
void moe_gemm(const unsigned short* __restrict__ xhi, const unsigned short* __restrict__ xlo,
              const unsigned short* __restrict__ whi, const unsigned short* __restrict__ wlo,
              const float* __restrict__ bias, const int* __restrict__ cnt,
              const int* __restrict__ bucket, float* __restrict__ out) {
  // XCD swizzle: bid&7 = XCD residue = expert; consecutive blocks on one XCD share
  // the A M-tile across 8 N-tiles (kept: FETCH halved in round 5).
  const int bid = blockIdx.x;
  const int e = bid & 7;
  const int rem = bid >> 3;
  const int my = rem >> 3;  // 0..63 M-tile (most early-exit; ~8 active per expert)
  const int nb = rem & 7;   // 0..7  N-tile
  const int count = cnt[e];
  const int m0 = my * BM;
  if (m0 >= count) return;  // uniform early exit before any barrier
  const int n0 = nb * BN;

  __shared__ __align__(16) char sbuf[2][65536];
  __shared__ int rowtok[BM];

  const int tid = threadIdx.x;
  const int lane = tid & 63;
  const int w = tid >> 6;
  const int wr = w >> 2;  // 0..1: wave owns 128 A-rows
  const int wc = w & 3;   // 0..3: wave owns 64 B-cols

  if (tid < BM) {
    int r = m0 + tid;
    rowtok[tid] = bucket[e * N_TOK + (r < count ? r : count - 1)];
  }
  __syncthreads();

  // Staging: 8 rounds x 512 threads x 16B = 64KB/K-tile. Round q (q<4: A, q>=4: B)
  // covers rows (q&3)*64 + (tid>>3); phys chunk tid&7; logical c = (tid&7)^(row&7);
  // c<4 -> hi array chunk c, c>=4 -> lo array chunk c-4.
  const unsigned short* whiE = whi + (size_t)e * D_OUT * D_IN;
  const unsigned short* wloE = wlo + (size_t)e * D_OUT * D_IN;
  const unsigned short* srcb[8];
  {
    const int g = tid >> 3;
    const int c = (tid & 7) ^ (g & 7);
    const int half = c >> 2, kc = c & 3;
#pragma unroll
    for (int q = 0; q < 4; ++q) {
      const int tok = rowtok[q * 64 + g];
      srcb[q] = (half ? xlo : xhi) + (size_t)tok * D_IN + kc * 8;
    }
#pragma unroll
    for (int q = 0; q < 4; ++q) {
      srcb[4 + q] = (half ? wloE : whiE) + (size_t)(n0 + q * 64 + g) * D_IN + kc * 8;
    }
  }
  const int dstw = w * 1024;  // wave-uniform LDS dest base (+ lane*16 implicit)

  // ds-read: row = R0(mult of 16) + (lane&15) => row&7 == lane&7;
  // hi chunk = lane>>4, phys = (lane>>4)^(lane&7); lo = phys^4 => byte off ^ 64.
  const int off0 = (lane & 15) * 128 + (((lane >> 4) ^ (lane & 7)) * 16);

  f32x4 acc[8][4];
#pragma unroll
  for (int i = 0; i < 8; ++i)
#pragma unroll
    for (int j = 0; j < 4; ++j) acc[i][j] = (f32x4)0.0f;

  // Prologue: stage tile 0 into buf 0.
#pragma unroll
  for (int q = 0; q < 8; ++q)
    GLD16(srcb[q], sbuf[0] + (q < 4 ? 0 : 32768) + (q & 3) * 8192 + dstw);

  for (int i = 0; i < NKT; ++i) {
    const char* rb = sbuf[i & 1];
    char* wb = sbuf[(i + 1) & 1];

    BAR();  // WAR gate: all waves done reading wb (during iter i-1)
    SB();
    if (i + 1 < NKT) {
      const int kt = (i + 1) * BK;
#pragma unroll
      for (int q = 0; q < 8; ++q)
        GLD16(srcb[q] + kt, wb + (q < 4 ? 0 : 32768) + (q & 3) * 8192 + dstw);
      // outstanding = 16; wait oldest 8 (tile i, in flight for a full iteration)
      asm volatile("s_waitcnt vmcnt(8)" ::: "memory");
    } else {
      asm volatile("s_waitcnt vmcnt(0)" ::: "memory");
    }
    BAR();  // all waves' tile-i slices landed
    SB();

#pragma unroll
    for (int mh = 0; mh < 2; ++mh) {
      bf16x8 ah[4], al[4], bh[4], bl[4];
#pragma unroll
      for (int mf = 0; mf < 4; ++mf) {
        const char* p = rb + (wr * 128 + mh * 64 + mf * 16) * 128;
        ah[mf] = *(const bf16x8*)(p + off0);
        al[mf] = *(const bf16x8*)(p + (off0 ^ 64));
      }
#pragma unroll
      for (int nf = 0; nf < 4; ++nf) {
        const char* p = rb + 32768 + (wc * 64 + nf * 16) * 128;
        bh[nf] = *(const bf16x8*)(p + off0);
        bl[nf] = *(const bf16x8*)(p + (off0 ^ 64));
      }
      __builtin_amdgcn_s_setprio(1);
#pragma unroll
      for (int mf = 0; mf < 4; ++mf)
#pragma unroll
        for (int nf = 0; nf < 4; ++nf) {
          f32x4 a = acc[mh * 4 + mf][nf];
          a = __builtin_amdgcn_mfma_f32_16x16x32_bf16(ah[mf], bh[nf], a, 0, 0, 0);
          a = __builtin_amdgcn_mfma_f32_16x16x32_bf16(ah[mf], bl[nf], a, 0, 0, 0);
          a = __builtin_amdgcn_mfma_f32_16x16x32_bf16(al[mf], bh[nf], a, 0, 0, 0);
          acc[mh * 4 + mf][nf] = a;
        }
      __builtin_amdgcn_s_setprio(0);
      if (mh == 0) { BAR(); }  // phase cohesion
    }
  }

  // epilogue: bias + ReLU + scatter (C/D: col=lane&15, row=(lane>>4)*4+i)
  const int r16 = lane & 15;
  const int rb4 = (lane >> 4) * 4;
#pragma unroll
  for (int n = 0; n < 4; ++n) {
    const int gn = n0 + wc * 64 + n * 16 + r16;
    const float bv = bias[e * D_OUT + gn];
#pragma unroll
    for (int m = 0; m < 8; ++m) {
      const int lr = wr * 128 + m * 16 + rb4;
#pragma unroll
      for (int i2 = 0; i2 < 4; ++i2) {
        const int row = lr + i2;
        if (m0 + row < count) {
          out[(size_t)rowtok[row] * D_OUT + gn] = fmaxf(acc[m][n][i2] + bv, 0.0f);
        }
      }
    }
  }
}

// ---------------- slow-but-correct fallback (only if ws too small) ----------------
__global__ void fallback_kernel(const float* __restrict__ x, const int* __restrict__ idxs,
                                const float* __restrict__ W, const float* __restrict__ b,
                                float* __restrict__ out) {
  const int row = blockIdx.y;
  const int col = blockIdx.x * 256 + threadIdx.x;
  const int e = idxs[row];
  const float4* xr = (const float4*)(x + (size_t)row * D_IN);
  const float4* wr = (const float4*)(W + ((size_t)e * D_OUT + col) * D_IN);
  float acc = 0.f;
  for (int k = 0; k < D_IN / 4; ++k) {
    float4 a = xr[k], w = wr[k];
    acc += a.x * w.x + a.y * w.y + a.z * w.z + a.w * w.w;
  }
  out[(size_t)row * D_OUT + col] = fmaxf(acc + b[e * D_OUT + col], 0.0f);
}

extern "C" void kernel_launch(void* const* d_in, const int* in_sizes, int n_in,
                              void* d_out, int out_size, void* d_ws, size_t ws_size,
                              hipStream_t stream) {
  const float* x = (const float*)d_in[0];
  const int* idxs = (const int*)d_in[1];
  const float* W = (const float*)d_in[2];
  const float* b = (const float*)d_in[3];
  float* out = (float*)d_out;

  size_t off = 0;
  auto alloc = [&](size_t bytes) {
    void* p = (char*)d_ws + off;
    off += (bytes + 255) & ~(size_t)255;
    return p;
  };
  int* cnt = (int*)alloc(NEXP * sizeof(int));
  int* bucket = (int*)alloc((size_t)NEXP * N_TOK * sizeof(int));
  unsigned short* xhi = (unsigned short*)alloc((size_t)N_TOK * D_IN * 2);
  unsigned short* xlo = (unsigned short*)alloc((size_t)N_TOK * D_IN * 2);
  unsigned short* whi = (unsigned short*)alloc((size_t)NEXP * D_OUT * D_IN * 2);
  unsigned short* wlo = (unsigned short*)alloc((size_t)NEXP * D_OUT * D_IN * 2);

  if (off > ws_size) {
    dim3 g(D_OUT / 256, N_TOK, 1);
    fallback_kernel<<<g, 256, 0, stream>>>(x, idxs, W, b, out);
    return;
  }

  zero_cnt<<<1, 64, 0, stream>>>(cnt);
  route_kernel<<<N_TOK / 256, 256, 0, stream>>>(idxs, cnt, bucket);
  split_both<<<2048, 256, 0, stream>>>(x, W, xhi, xlo, whi, wlo);

  const int nblk = NEXP * (N_TOK / BM) * (D_OUT / BN);  // 8*64*8 = 4096
  moe_gemm<<<nblk, 512, 0, stream>>>(xhi, xlo, whi, wlo, b, cnt, bucket, out);
}